// Round 3
// baseline (953.873 us; speedup 1.0000x reference)
//
#include <hip/hip_runtime.h>

#define Bb 2
#define Nn 256
#define Dd 128
#define Rr 32

typedef __attribute__((ext_vector_type(4))) float f32x4;

// ---- kernel 1: h = node_s @ src_w  (fp32) ----------------------------------
__global__ __launch_bounds__(128) void hproj_kernel(
    const float* __restrict__ node_s, const float* __restrict__ src_w,
    float* __restrict__ h_out){
  __shared__ float s_row[Dd];
  const int bi = blockIdx.x, d = threadIdx.x;
  s_row[d] = node_s[(size_t)bi*Dd + d];
  __syncthreads();
  float acc = 0.f;
  #pragma unroll 8
  for (int k=0;k<Dd;k++) acc += s_row[k]*src_w[k*Dd + d];
  h_out[(size_t)bi*Dd + d] = acc;
}

// ---- kernel 2: naive fp32 reference path, one block per (b,i) --------------
__global__ __launch_bounds__(256) void se3_naive(
    const float* __restrict__ node_v,
    const float* __restrict__ rbf,
    const float* __restrict__ r_hat,
    const float* __restrict__ maskp,
    const float* __restrict__ r0w1, const float* __restrict__ r0b1,
    const float* __restrict__ r0w2, const float* __restrict__ r0b2,
    const float* __restrict__ r1w1, const float* __restrict__ r1b1,
    const float* __restrict__ r1w2, const float* __restrict__ r1b2,
    const float* __restrict__ r2w1, const float* __restrict__ r2b1,
    const float* __restrict__ r2w2, const float* __restrict__ r2b2,
    const float* __restrict__ r3w1, const float* __restrict__ r3b1,
    const float* __restrict__ r3w2, const float* __restrict__ r3b2,
    const float* __restrict__ ln_g, const float* __restrict__ ln_b,
    const float* __restrict__ out_w, const float* __restrict__ out_b,
    const float* __restrict__ v_scale, const float* __restrict__ t_scale,
    const float* __restrict__ h_ws,
    float* __restrict__ out_s, float* __restrict__ out_v, float* __restrict__ out_t)
{
  __shared__ float s_w1[Rr*Dd];        // 16384 B
  __shared__ float s_rbf[32*Rr];       // 4096 B (one 32-j chunk)
  __shared__ float s_hid[Dd][16];      // 8192 B (16 j's, transposed)
  __shared__ float s_Y1[Nn*3];         // 3072 B
  __shared__ float s_Y2[Nn*5];         // 5120 B
  __shared__ float s_mask[Nn];         // 1024 B
  __shared__ float s_b1[Dd], s_b2[Dd]; // 1024 B
  __shared__ float s_red[Dd][10];      // 5120 B
  __shared__ float s_msg[Dd], s_xn[Dd];// 1024 B
  __shared__ float s_part[2*Dd];       // 1024 B
  __shared__ float s_mv[2];            // 8 B

  const int tid = threadIdx.x;
  const int bi  = blockIdx.x;          // b*N + i
  const int b   = bi >> 8;
  const int d   = tid & 127;
  const int jh  = tid >> 7;            // 0 or 1: which 8-j half of a 16-j batch

  // ---- setup: mask, Y1, Y2 (one j per thread) ----
  {
    int j = tid;
    size_t pidx = (size_t)bi*Nn + j;
    s_mask[j] = maskp[pidx];
    float x = r_hat[pidx*3+0];
    float y = r_hat[pidx*3+1];
    float z = r_hat[pidx*3+2];
    const float SQ3=1.7320508075688772f;   // sqrt(3)
    const float C15=3.8729833462074170f;   // sqrt(15)
    const float C5H=1.1180339887498949f;   // 0.5*sqrt(5)
    s_Y1[j*3+0]=SQ3*x; s_Y1[j*3+1]=SQ3*y; s_Y1[j*3+2]=SQ3*z;
    s_Y2[j*5+0]=C15*x*y;
    s_Y2[j*5+1]=C15*y*z;
    s_Y2[j*5+2]=C5H*(3.f*z*z-1.f);
    s_Y2[j*5+3]=C15*x*z;
    s_Y2[j*5+4]=0.5f*C15*(x*x-y*y);
  }

  // node_v[b,i,c,d] for this thread's d
  const float nv0 = node_v[(size_t)bi*3*Dd + 0*Dd + d];
  const float nv1 = node_v[(size_t)bi*3*Dd + 1*Dd + d];
  const float nv2 = node_v[(size_t)bi*3*Dd + 2*Dd + d];

  const float* W1a[4]={r0w1,r1w1,r2w1,r3w1};
  const float* B1a[4]={r0b1,r1b1,r2b1,r3b1};
  const float* W2a[4]={r0w2,r1w2,r2w2,r3w2};
  const float* B2a[4]={r0b2,r1b2,r2b2,r3b2};

  const float* rbf_blk = rbf + (size_t)bi*Nn*Rr;

  // accumulators: 0=msg_s, 1..3=delta_v(xyz), 4..8=delta_t, 9=msg_from_v
  float acc_[10];
  #pragma unroll
  for (int c=0;c<10;c++) acc_[c]=0.f;

  for (int p=0;p<4;p++){
    // ---- stage this MLP's w1/b1/b2 ----
    {
      const float* w1s=W1a[p];
      for (int idx=tid; idx<Rr*Dd; idx+=256) s_w1[idx]=w1s[idx];
      if (tid<Dd){ s_b1[tid]=B1a[p][tid]; s_b2[tid]=B2a[p][tid]; }
    }
    __syncthreads();

    // hoist w1 column d into registers
    float w1c[Rr];
    #pragma unroll
    for (int r=0;r<Rr;r++) w1c[r]=s_w1[r*Dd+d];

    const float* W2p = W2a[p];

    for (int jc=0;jc<8;jc++){            // 8 chunks of 32 j
      // stage rbf chunk: 32 j * 32 r
      {
        const float* rs = rbf_blk + (size_t)jc*32*Rr;
        for (int idx=tid; idx<32*Rr; idx+=256) s_rbf[idx]=rs[idx];
      }
      __syncthreads();

      for (int bt=0; bt<2; bt++){        // two 16-j batches per chunk
        const int jbase = jc*32 + bt*16;
        // ---- hidden = SiLU(rbf @ w1 + b1), transposed store s_hid[d][jslot]
        #pragma unroll 1
        for (int jj=0;jj<8;jj++){
          int jl = bt*16 + jh*8 + jj;    // chunk-local j
          float a = s_b1[d];
          #pragma unroll 8
          for (int r=0;r<Rr;r++) a += s_rbf[jl*Rr + r] * w1c[r];
          float sg = 1.f/(1.f+__expf(-a));
          s_hid[d][jh*8+jj] = a*sg;
        }
        __syncthreads();
        // ---- rad = hidden @ w2 + b2 for this thread's d, 8 j's
        float racc[8];
        #pragma unroll
        for (int jj=0;jj<8;jj++) racc[jj]=s_b2[d];
        #pragma unroll 4
        for (int k=0;k<Dd;k++){
          float wv = W2p[k*Dd+d];
          f32x4 h0 = *(const f32x4*)&s_hid[k][jh*8];
          f32x4 h1 = *(const f32x4*)&s_hid[k][jh*8+4];
          racc[0]+=wv*h0[0]; racc[1]+=wv*h0[1]; racc[2]+=wv*h0[2]; racc[3]+=wv*h0[3];
          racc[4]+=wv*h1[0]; racc[5]+=wv*h1[1]; racc[6]+=wv*h1[2]; racc[7]+=wv*h1[3];
        }
        // ---- accumulate message terms
        #pragma unroll 1
        for (int jj=0;jj<8;jj++){
          int j = jbase + jh*8 + jj;
          float rad = racc[jj];
          float mk  = s_mask[j];
          float hv  = h_ws[((size_t)b*Nn + j)*Dd + d];
          if (p==0){
            acc_[0] += hv*mk*rad;
          } else if (p==1){
            float a2 = hv*mk*rad;
            acc_[1]+=a2*s_Y1[j*3+0];
            acc_[2]+=a2*s_Y1[j*3+1];
            acc_[3]+=a2*s_Y1[j*3+2];
          } else if (p==2){
            float a2 = hv*mk*rad;
            #pragma unroll
            for (int c=0;c<5;c++) acc_[4+c]+=a2*s_Y2[j*5+c];
          } else {
            float dot = nv0*s_Y1[j*3+0]+nv1*s_Y1[j*3+1]+nv2*s_Y1[j*3+2];
            acc_[9] += dot*mk*rad;
          }
        }
        __syncthreads();                 // protect s_hid / s_rbf / s_w1
      }
    }
  }

  // ---- reduce across the two jh halves ----
  if (jh==1){
    #pragma unroll
    for (int c=0;c<10;c++) s_red[d][c]=acc_[c];
  }
  __syncthreads();
  if (tid < Dd){
    float tot[10];
    #pragma unroll
    for (int c=0;c<10;c++) tot[c]=acc_[c]+s_red[tid][c];
    s_msg[tid]=tot[0]+tot[9];
    float vs=v_scale[tid], ts=t_scale[tid];
    size_t ovb=(size_t)bi*3*Dd + tid;
    #pragma unroll
    for (int c=0;c<3;c++) out_v[ovb+(size_t)c*Dd]=tot[1+c]*vs;
    size_t otb=(size_t)bi*5*Dd + tid;
    #pragma unroll
    for (int c=0;c<5;c++) out_t[otb+(size_t)c*Dd]=tot[4+c]*ts;
  }
  __syncthreads();

  // ---- LayerNorm stats (wave 0), biased var, guarded ----
  if (tid < 64){
    float a0=s_msg[tid], a1=s_msg[tid+64];
    float s1=a0+a1, s2=a0*a0+a1*a1;
    #pragma unroll
    for (int off=1;off<64;off<<=1){
      s1 += __shfl_xor(s1,off);
      s2 += __shfl_xor(s2,off);
    }
    if (tid==0){
      float m   = s1*(1.f/Dd);
      float var = fmaxf(s2*(1.f/Dd) - m*m, 0.f);
      s_mv[0]=m;
      s_mv[1]=rsqrtf(var+1e-5f);
    }
  }
  __syncthreads();
  if (tid < Dd)
    s_xn[tid] = (s_msg[tid]-s_mv[0])*s_mv[1]*ln_g[tid] + ln_b[tid];
  __syncthreads();

  // ---- delta_s = xn @ out_w + out_b ----
  {
    int dp = tid & 127, seg = tid >> 7;
    float pa = 0.f;
    #pragma unroll 8
    for (int k=seg*64;k<seg*64+64;k++)
      pa += s_xn[k]*out_w[k*Dd+dp];
    s_part[seg*Dd+dp]=pa;
  }
  __syncthreads();
  if (tid < Dd)
    out_s[(size_t)bi*Dd+tid] = s_part[tid]+s_part[Dd+tid]+out_b[tid];
}

extern "C" void kernel_launch(void* const* d_in, const int* in_sizes, int n_in,
                              void* d_out, int out_size, void* d_ws, size_t ws_size,
                              hipStream_t stream) {
  const float* node_s = (const float*)d_in[0];
  const float* node_v = (const float*)d_in[1];
  // d_in[2] = node_t (unused by reference)
  const float* rbf    = (const float*)d_in[3];
  const float* r_hat  = (const float*)d_in[4];
  const float* maskp  = (const float*)d_in[5];
  const float* r0w1=(const float*)d_in[6],  *r0b1=(const float*)d_in[7];
  const float* r0w2=(const float*)d_in[8],  *r0b2=(const float*)d_in[9];
  const float* r1w1=(const float*)d_in[10], *r1b1=(const float*)d_in[11];
  const float* r1w2=(const float*)d_in[12], *r1b2=(const float*)d_in[13];
  const float* r2w1=(const float*)d_in[14], *r2b1=(const float*)d_in[15];
  const float* r2w2=(const float*)d_in[16], *r2b2=(const float*)d_in[17];
  const float* r3w1=(const float*)d_in[18], *r3b1=(const float*)d_in[19];
  const float* r3w2=(const float*)d_in[20], *r3b2=(const float*)d_in[21];
  const float* src_w  =(const float*)d_in[22];
  const float* ln_g   =(const float*)d_in[23];
  const float* ln_b   =(const float*)d_in[24];
  const float* out_w  =(const float*)d_in[25];
  const float* out_b  =(const float*)d_in[26];
  const float* v_scale=(const float*)d_in[27];
  const float* t_scale=(const float*)d_in[28];

  float* h_ws = (float*)d_ws;                    // 512*128 f32 = 256 KiB
  float* out_s = (float*)d_out;
  float* out_v = out_s + (size_t)Bb*Nn*Dd;
  float* out_t = out_v + (size_t)Bb*Nn*3*Dd;

  hproj_kernel<<<dim3(Bb*Nn), dim3(Dd), 0, stream>>>(node_s, src_w, h_ws);
  se3_naive<<<dim3(Bb*Nn), dim3(256), 0, stream>>>(
      node_v, rbf, r_hat, maskp,
      r0w1,r0b1,r0w2,r0b2, r1w1,r1b1,r1w2,r1b2,
      r2w1,r2b1,r2w2,r2b2, r3w1,r3b1,r3w2,r3b2,
      ln_g, ln_b, out_w, out_b, v_scale, t_scale,
      h_ws, out_s, out_v, out_t);
}